// Round 5
// baseline (5640.396 us; speedup 1.0000x reference)
//
#include <hip/hip_runtime.h>
#include <hip/hip_bf16.h>
#include <hip/hip_fp16.h>
#include <stdint.h>

// Problem dims
#define BB 128
#define TT 512
#define HH 256
#define VV 29
#define NSTEP 63
#define BT (BB*TT)
#define CHUNK 64   // layer-1 time chunk

typedef _Float16 f16;
typedef _Float16 f16x2 __attribute__((ext_vector_type(2)));
typedef _Float16 f16x8 __attribute__((ext_vector_type(8)));
typedef float f32x4 __attribute__((ext_vector_type(4)));

static __device__ __forceinline__ float fdot2u(uint32_t a, uint32_t b, float c) {
  return __builtin_amdgcn_fdot2(__builtin_bit_cast(f16x2, a),
                                __builtin_bit_cast(f16x2, b), c, false);
}
static __device__ __forceinline__ float sigm_(float x) {
  return 1.0f / (1.0f + __expf(-x));
}

// ---------------- fp32 -> f16 convert ----------------
__global__ void k_cvt(const float* __restrict__ s, f16* __restrict__ d, int n) {
  int i = blockIdx.x * 256 + threadIdx.x;
  if (i < n) d[i] = (f16)s[i];
}

// ---------------- persistent GRU scan: 1 WG per (batch, dir) ----------------
template<int LAYER>
__global__ __launch_bounds__(512, 2)
void k_scan(const float* __restrict__ x,        // L0: (B,T,2)
            const f16* __restrict__ gi,         // L1: (B,nsteps,1536) chunk-local
            const uint32_t* __restrict__ whh,   // (2,768,128) as half2
            const float* __restrict__ wih0,     // L0: (2,768,2)
            const float* __restrict__ bih,      // L0: (2,768)
            const float* __restrict__ bhh,      // (2,768)
            f16* __restrict__ y,                // (B,T,512) [t][dir*256+p]
            float* __restrict__ hstate,         // (2,B,256) f32
            int t0, int nsteps)
{
  const int wg = blockIdx.x, b = wg >> 1, dir = wg & 1;
  const int tid = threadIdx.x, pair = tid >> 1, half = tid & 1;
  __shared__ __align__(16) uint4 hv4[32];   // h as f16[256]

  uint4 w0[16], w1[16], w2[16];
  {
    const uint32_t* wp = whh + (size_t)dir * 768 * 128;
    const uint4* r0 = (const uint4*)(wp + (size_t)pair * 128 + half * 64);
    const uint4* r1 = (const uint4*)(wp + (size_t)(pair + 256) * 128 + half * 64);
    const uint4* r2 = (const uint4*)(wp + (size_t)(pair + 512) * 128 + half * 64);
#pragma unroll
    for (int i = 0; i < 16; i++) { w0[i] = r0[i]; w1[i] = r1[i]; w2[i] = r2[i]; }
  }
  const float bh0 = bhh[dir * 768 + pair];
  const float bh1 = bhh[dir * 768 + pair + 256];
  const float bh2 = bhh[dir * 768 + pair + 512];
  float bi0 = 0, bi1 = 0, bi2 = 0;
  float wi00 = 0, wi01 = 0, wi10 = 0, wi11 = 0, wi20 = 0, wi21 = 0;
  if (LAYER == 0) {
    bi0 = bih[dir * 768 + pair];
    bi1 = bih[dir * 768 + pair + 256];
    bi2 = bih[dir * 768 + pair + 512];
    wi00 = wih0[(dir * 768 + pair) * 2 + 0];
    wi01 = wih0[(dir * 768 + pair) * 2 + 1];
    wi10 = wih0[(dir * 768 + pair + 256) * 2 + 0];
    wi11 = wih0[(dir * 768 + pair + 256) * 2 + 1];
    wi20 = wih0[(dir * 768 + pair + 512) * 2 + 0];
    wi21 = wih0[(dir * 768 + pair + 512) * 2 + 1];
  }
  float* hs = hstate + ((size_t)dir * BB + b) * 256;
  float hreg = hs[pair];
  if (tid < 128) {
    f16x2 p2; p2[0] = (f16)hs[2 * tid]; p2[1] = (f16)hs[2 * tid + 1];
    ((uint32_t*)hv4)[tid] = __builtin_bit_cast(uint32_t, p2);
  }
  __syncthreads();

  const uint4* hw = hv4 + half * 16;
  for (int s = 0; s < nsteps; ++s) {
    const int t = dir ? (TT - 1 - t0 - s) : (t0 + s);
    float gr, gz, gn;
    if (LAYER == 0) {
      float x0 = x[((size_t)b * TT + t) * 2 + 0];
      float x1 = x[((size_t)b * TT + t) * 2 + 1];
      gr = wi00 * x0 + wi01 * x1 + bi0;
      gz = wi10 * x0 + wi11 * x1 + bi1;
      gn = wi20 * x0 + wi21 * x1 + bi2;
    } else {
      const f16* g = gi + ((size_t)b * nsteps + s) * 1536 + dir * 768 + pair;
      gr = (float)g[0]; gz = (float)g[256]; gn = (float)g[512];
    }
    float a0 = 0.f, a1 = 0.f, a2 = 0.f;
#pragma unroll
    for (int j = 0; j < 16; ++j) {
      uint4 hh = hw[j];
      a0 = fdot2u(w0[j].x, hh.x, a0); a0 = fdot2u(w0[j].y, hh.y, a0);
      a0 = fdot2u(w0[j].z, hh.z, a0); a0 = fdot2u(w0[j].w, hh.w, a0);
      a1 = fdot2u(w1[j].x, hh.x, a1); a1 = fdot2u(w1[j].y, hh.y, a1);
      a1 = fdot2u(w1[j].z, hh.z, a1); a1 = fdot2u(w1[j].w, hh.w, a1);
      a2 = fdot2u(w2[j].x, hh.x, a2); a2 = fdot2u(w2[j].y, hh.y, a2);
      a2 = fdot2u(w2[j].z, hh.z, a2); a2 = fdot2u(w2[j].w, hh.w, a2);
    }
    a0 += __shfl_xor(a0, 1);
    a1 += __shfl_xor(a1, 1);
    a2 += __shfl_xor(a2, 1);

    float r = sigm_(gr + a0 + bh0);
    float z = sigm_(gz + a1 + bh1);
    float n = tanhf(gn + r * (a2 + bh2));
    float hn = (1.0f - z) * n + z * hreg;
    hreg = hn;
    if (half == 0) y[((size_t)b * TT + t) * 512 + dir * 256 + pair] = (f16)hn;
    __syncthreads();
    if (half == 0) ((f16*)hv4)[pair] = (f16)hn;
    __syncthreads();
  }
  if (half == 0) hs[pair] = hreg;
}

// ---------------- f16 MFMA GEMM ----------------
__global__ __launch_bounds__(256)
void k_gemm(const f16* __restrict__ A, const f16* __restrict__ Bt,
            f16* __restrict__ C, const float* __restrict__ bias,
            int K, int shift, long bstride, int inner, int ldc, int coloff)
{
  const int m0 = blockIdx.x * 64, n0 = blockIdx.y * 64;
  const int tid = threadIdx.x, lane = tid & 63, wv = tid >> 6;
  __shared__ __align__(16) f16 As[64 * 40];
  __shared__ __align__(16) f16 Bs[64 * 40];
  f32x4 acc[4] = {{0,0,0,0},{0,0,0,0},{0,0,0,0},{0,0,0,0}};
  const int lrow = tid >> 2, lseg = tid & 3;
  const int ml = lane & 15, quad = lane >> 4;
  const int r = m0 + lrow;
  const f16* arow = A + (long)(r >> shift) * bstride
                      + (long)(r & ((1 << shift) - 1)) * inner;
  const f16* brow = Bt + (size_t)(n0 + lrow) * K;
  for (int k0 = 0; k0 < K; k0 += 32) {
    uint4 av = *(const uint4*)(arow + k0 + lseg * 8);
    uint4 bv = *(const uint4*)(brow + k0 + lseg * 8);
    __syncthreads();
    *(uint4*)(As + lrow * 40 + lseg * 8) = av;
    *(uint4*)(Bs + lrow * 40 + lseg * 8) = bv;
    __syncthreads();
    f16x8 af = *(const f16x8*)(As + (wv * 16 + ml) * 40 + quad * 8);
#pragma unroll
    for (int ns = 0; ns < 4; ++ns) {
      f16x8 bf = *(const f16x8*)(Bs + (ns * 16 + ml) * 40 + quad * 8);
      acc[ns] = __builtin_amdgcn_mfma_f32_16x16x32_f16(af, bf, acc[ns], 0, 0, 0);
    }
  }
#pragma unroll
  for (int ns = 0; ns < 4; ++ns) {
#pragma unroll
    for (int rr = 0; rr < 4; ++rr) {
      int row = m0 + wv * 16 + quad * 4 + rr;
      int col = n0 + ns * 16 + ml;
      float v = acc[ns][rr];
      if (bias) v += bias[col];
      C[(size_t)row * ldc + coloff + col] = (f16)v;
    }
  }
}

// ---------------- decoder helpers ----------------
// 256-element dot: w,h = 32 uint4 (8 f16 each)
static __device__ __forceinline__ float dot256(const uint4* __restrict__ w,
                                               const uint4* __restrict__ h) {
  float g = 0.f;
#pragma unroll 8
  for (int j = 0; j < 32; ++j) {
    uint4 a = w[j], b = h[j];
    g = fdot2u(a.x, b.x, g); g = fdot2u(a.y, b.y, g);
    g = fdot2u(a.z, b.z, g); g = fdot2u(a.w, b.w, g);
  }
  return g;
}
// 128-element dot: 16 uint4
static __device__ __forceinline__ float dot128(const uint4* __restrict__ w,
                                               const uint4* __restrict__ h) {
  float g = 0.f;
#pragma unroll 8
  for (int j = 0; j < 16; ++j) {
    uint4 a = w[j], b = h[j];
    g = fdot2u(a.x, b.x, g); g = fdot2u(a.y, b.y, g);
    g = fdot2u(a.z, b.z, g); g = fdot2u(a.w, b.w, g);
  }
  return g;
}
static __device__ __forceinline__ float edot(uint4 w, const float* e) {
  f16x2 a = __builtin_bit_cast(f16x2, w.x);
  f16x2 b = __builtin_bit_cast(f16x2, w.y);
  f16x2 c = __builtin_bit_cast(f16x2, w.z);
  f16x2 d = __builtin_bit_cast(f16x2, w.w);
  return (float)a[0]*e[0] + (float)a[1]*e[1] + (float)b[0]*e[2] + (float)b[1]*e[3]
       + (float)c[0]*e[4] + (float)c[1]*e[5] + (float)d[0]*e[6] + (float)d[1]*e[7];
}

// ---------------- persistent decoder: 1 WG(768 thr) per batch, 63 steps ------
__global__ __launch_bounds__(768, 3)
void k_decoder(const f16* __restrict__ dwhh,   // (2,768,256)
               const f16* __restrict__ dwih1,  // (768,256)
               const f16* __restrict__ dwih0,  // (768,8)
               const f16* __restrict__ qw,     // (256,256)
               const f16* __restrict__ outw,   // (29,256)
               const f16* __restrict__ enc,    // (B,512,256)
               const float* __restrict__ dbih, // (2,768)
               const float* __restrict__ dbhh, // (2,768)
               const float* __restrict__ qb, const float* __restrict__ outb,
               const float* __restrict__ emb,  // (29,8)
               const float* __restrict__ hs0, const float* __restrict__ hs1,
               const int* __restrict__ tseq,
               float* __restrict__ out)
{
  const int b = blockIdx.x, tid = threadIdx.x;
  __shared__ __align__(16) f16 h0sh[256], h1sh[256], qsh[256];
  __shared__ float h1f[256];
  __shared__ float g0sh[768], g1sh[768], gi0n[256], gi1sh[768];
  __shared__ float qpart[2][256];
  __shared__ float sc[512];
  __shared__ float redm[12], redl[12];
  __shared__ __align__(16) float cpart[4][256];
  __shared__ __align__(16) float hc[256];
  __shared__ float lg[32];
  __shared__ float e8[8];
  __shared__ int toksh;

  if (tid < 256) {
    h0sh[tid] = (f16)(hs0[b * 256 + tid] + hs0[32768 + b * 256 + tid]);
    h1sh[tid] = (f16)(hs1[b * 256 + tid] + hs1[32768 + b * 256 + tid]);
  }
  if (tid == 0) {
    int tk = tseq[b * 64]; toksh = tk;
    for (int k = 0; k < 8; ++k) e8[k] = emb[tk * 8 + k];
  }
  __syncthreads();

  const int wvi = tid >> 6;

  for (int s = 0; s < NSTEP; ++s) {
    // ---- phase 1: gh0 (dwhh0@h0_old) + gi0 (emb) and gh1 (dwhh1@h1_old) ----
    {
      const uint4* wA = (const uint4*)(dwhh + (size_t)tid * 256);
      const uint4* wB = (const uint4*)(dwhh + (size_t)(768 + tid) * 256);
      const uint4* h0q = (const uint4*)h0sh;
      const uint4* h1q = (const uint4*)h1sh;
      float gA = dbhh[tid], gB = dbhh[768 + tid];
#pragma unroll 8
      for (int j = 0; j < 32; ++j) {
        uint4 a = wA[j], ha = h0q[j];
        uint4 c = wB[j], hb = h1q[j];
        gA = fdot2u(a.x, ha.x, gA); gA = fdot2u(a.y, ha.y, gA);
        gA = fdot2u(a.z, ha.z, gA); gA = fdot2u(a.w, ha.w, gA);
        gB = fdot2u(c.x, hb.x, gB); gB = fdot2u(c.y, hb.y, gB);
        gB = fdot2u(c.z, hb.z, gB); gB = fdot2u(c.w, hb.w, gB);
      }
      uint4 wi = *(const uint4*)(dwih0 + (size_t)tid * 8);
      float gi = dbih[tid] + edot(wi, e8);
      if (tid < 512) g0sh[tid] = gA + gi;
      else { g0sh[tid] = gA; gi0n[tid - 512] = gi; }
      g1sh[tid] = gB;
    }
    __syncthreads();

    // ---- gates0: h0' ----
    if (tid < 256) {
      float r = sigm_(g0sh[tid]);
      float z = sigm_(g0sh[tid + 256]);
      float n = tanhf(gi0n[tid] + r * g0sh[tid + 512]);
      float hp = (float)h0sh[tid];
      h0sh[tid] = (f16)((1.f - z) * n + z * hp);
    }
    __syncthreads();

    // ---- gi1 = dwih1 @ h0' + dbih1 ----
    gi1sh[tid] = dbih[768 + tid] +
                 dot256((const uint4*)(dwih1 + (size_t)tid * 256), (const uint4*)h0sh);
    __syncthreads();

    // ---- gates1: h1' ----
    if (tid < 256) {
      float r = sigm_(gi1sh[tid] + g1sh[tid]);
      float z = sigm_(gi1sh[tid + 256] + g1sh[tid + 256]);
      float n = tanhf(gi1sh[tid + 512] + r * g1sh[tid + 512]);
      float hp = (float)h1sh[tid];
      float hn = (1.f - z) * n + z * hp;
      h1f[tid] = hn;
      h1sh[tid] = (f16)hn;
    }
    __syncthreads();

    // ---- q = qW @ h1' + qb (k-split over 512 threads) ----
    if (tid < 512) {
      int row = tid & 255, kh = tid >> 8;
      qpart[kh][row] = dot128((const uint4*)(qw + (size_t)row * 256 + kh * 128),
                              (const uint4*)h1sh + kh * 16);
    }
    __syncthreads();
    if (tid < 256) qsh[tid] = (f16)(qpart[0][tid] + qpart[1][tid] + qb[tid]);
    __syncthreads();

    // ---- scores ----
    if (tid < 512)
      sc[tid] = dot256((const uint4*)(enc + ((size_t)b * 512 + tid) * 256),
                       (const uint4*)qsh);
    __syncthreads();

    // ---- softmax ----
    float v = (tid < 512) ? sc[tid] : -1e30f;
    float mloc = v;
#pragma unroll
    for (int off = 32; off; off >>= 1) mloc = fmaxf(mloc, __shfl_xor(mloc, off));
    if ((tid & 63) == 0) redm[wvi] = mloc;
    __syncthreads();
    float m = redm[0];
#pragma unroll
    for (int i = 1; i < 12; ++i) m = fmaxf(m, redm[i]);
    float e = 0.f;
    if (tid < 512) { e = __expf(v - m); sc[tid] = e; }
    float lloc = e;
#pragma unroll
    for (int off = 32; off; off >>= 1) lloc += __shfl_xor(lloc, off);
    if ((tid & 63) == 0) redl[wvi] = lloc;
    __syncthreads();
    float l = redl[0];
#pragma unroll
    for (int i = 1; i < 12; ++i) l += redl[i];

    // ---- ctx: (channel-pair, t-quarter) over 512 threads ----
    if (tid < 512) {
      const int c2 = tid & 127, seg = tid >> 7;
      const uint32_t* eb = (const uint32_t*)enc + (((size_t)b * 512 + seg * 128) * 128) + c2;
      const float* wsc = sc + seg * 128;
      float c0 = 0.f, c1 = 0.f;
#pragma unroll 8
      for (int i = 0; i < 128; ++i) {
        uint32_t vv = eb[(size_t)i * 128];
        float wgt = wsc[i];
        f16x2 h2 = __builtin_bit_cast(f16x2, vv);
        c0 += wgt * (float)h2[0];
        c1 += wgt * (float)h2[1];
      }
      ((float2*)cpart[seg])[c2] = float2{c0, c1};
    }
    __syncthreads();
    if (tid < 256)
      hc[tid] = (cpart[0][tid] + cpart[1][tid] + cpart[2][tid] + cpart[3][tid]) / l
                + h1f[tid];
    __syncthreads();

    // ---- logits (29x256, 8 threads per row) + write ----
    if (tid < VV * 8) {
      const int vv = tid >> 3, kseg = tid & 7;
      float acc = 0.f;
      const uint4* ow = (const uint4*)(outw + (size_t)vv * 256 + kseg * 32);
      const float4* hv = (const float4*)(hc + kseg * 32);
#pragma unroll
      for (int j = 0; j < 4; ++j) {
        uint4 wq = ow[j];
        float4 ha = hv[2 * j], hb = hv[2 * j + 1];
        f16x2 p0 = __builtin_bit_cast(f16x2, wq.x);
        f16x2 p1 = __builtin_bit_cast(f16x2, wq.y);
        f16x2 p2 = __builtin_bit_cast(f16x2, wq.z);
        f16x2 p3 = __builtin_bit_cast(f16x2, wq.w);
        acc += (float)p0[0]*ha.x + (float)p0[1]*ha.y + (float)p1[0]*ha.z + (float)p1[1]*ha.w;
        acc += (float)p2[0]*hb.x + (float)p2[1]*hb.y + (float)p3[0]*hb.z + (float)p3[1]*hb.w;
      }
      acc += __shfl_xor(acc, 1);
      acc += __shfl_xor(acc, 2);
      acc += __shfl_xor(acc, 4);
      if (kseg == 0) {
        float lv = acc + outb[vv];
        lg[vv] = lv;
        out[((size_t)b * NSTEP + s) * VV + vv] = lv;
      }
    }
    __syncthreads();
    if (tid == 0) {
      int best = 0; float bv = lg[0];
      for (int v2 = 1; v2 < VV; ++v2) if (lg[v2] > bv) { bv = lg[v2]; best = v2; }
      toksh = best;
      for (int k = 0; k < 8; ++k) e8[k] = emb[best * 8 + k];
    }
    __syncthreads();
  }

  if (tid < 256) {
    out[233856 + b * 256 + tid] = (float)h0sh[tid];
    out[233856 + 32768 + b * 256 + tid] = (float)h1sh[tid];
  }
}

extern "C" void kernel_launch(void* const* d_in, const int* in_sizes, int n_in,
                              void* d_out, int out_size, void* d_ws, size_t ws_size,
                              hipStream_t stream) {
  (void)in_sizes; (void)n_in; (void)out_size; (void)ws_size;
  const float* x     = (const float*)d_in[0];
  const int*   tseq  = (const int*)d_in[1];
  const float* eWih0 = (const float*)d_in[2];
  const float* eWhh0 = (const float*)d_in[3];
  const float* ebih0 = (const float*)d_in[4];
  const float* ebhh0 = (const float*)d_in[5];
  const float* eWih1 = (const float*)d_in[6];
  const float* eWhh1 = (const float*)d_in[7];
  const float* ebih1 = (const float*)d_in[8];
  const float* ebhh1 = (const float*)d_in[9];
  const float* e2dW  = (const float*)d_in[10];
  const float* e2db  = (const float*)d_in[11];
  const float* dWih0 = (const float*)d_in[12];
  const float* dWih1 = (const float*)d_in[13];
  const float* dWhh  = (const float*)d_in[14];
  const float* dbih  = (const float*)d_in[15];
  const float* dbhh  = (const float*)d_in[16];
  const float* qW    = (const float*)d_in[17];
  const float* qb    = (const float*)d_in[18];
  const float* outW  = (const float*)d_in[19];
  const float* outb  = (const float*)d_in[20];
  const float* emb   = (const float*)d_in[21];

  uint8_t* ws = (uint8_t*)d_ws;
  size_t o = 0;
  auto take = [&](size_t bytes) -> void* {
    void* p = ws + o;
    o += (bytes + 255) & ~(size_t)255;
    return p;
  };
  f16* whh0_16  = (f16*)take((size_t)2 * 768 * 256 * 2);
  f16* whh1_16  = (f16*)take((size_t)2 * 768 * 256 * 2);
  f16* wih1_16  = (f16*)take((size_t)2 * 768 * 512 * 2);
  f16* e2d_16   = (f16*)take((size_t)256 * 512 * 2);
  f16* qw_16    = (f16*)take((size_t)256 * 256 * 2);
  f16* outw_16  = (f16*)take((size_t)29 * 256 * 2);
  f16* dwih0_16 = (f16*)take((size_t)768 * 8 * 2);
  f16* dwih1_16 = (f16*)take((size_t)768 * 256 * 2);
  f16* dwhh_16  = (f16*)take((size_t)2 * 768 * 256 * 2);
  f16* y0   = (f16*)take((size_t)BT * 512 * 2);          // enc aliases later
  f16* y1   = (f16*)take((size_t)BT * 512 * 2);
  f16* gi   = (f16*)take((size_t)BB * CHUNK * 1536 * 2); // rolling chunk
  float* hs0 = (float*)take((size_t)2 * BB * 256 * 4);
  float* hs1 = (float*)take((size_t)2 * BB * 256 * 4);
  f16* enc = y0;  // alias: y0 dead after last gi chunk GEMM

  hipMemsetAsync(hs0, 0, (size_t)2 * BB * 256 * 4, stream);
  hipMemsetAsync(hs1, 0, (size_t)2 * BB * 256 * 4, stream);

  auto cvt = [&](const float* s, f16* d, int n) {
    k_cvt<<<(n + 255) / 256, 256, 0, stream>>>(s, d, n);
  };
  cvt(eWhh0, whh0_16, 2 * 768 * 256);
  cvt(eWhh1, whh1_16, 2 * 768 * 256);
  cvt(eWih1, wih1_16, 2 * 768 * 512);
  cvt(e2dW,  e2d_16,  256 * 512);
  cvt(qW,    qw_16,   256 * 256);
  cvt(outW,  outw_16, 29 * 256);
  cvt(dWih0, dwih0_16, 768 * 8);
  cvt(dWih1, dwih1_16, 768 * 256);
  cvt(dWhh,  dwhh_16, 2 * 768 * 256);

  // encoder layer 0 (both dirs, full T; gi inline since IN=2)
  k_scan<0><<<256, 512, 0, stream>>>(x, nullptr, (const uint32_t*)whh0_16,
                                     eWih0, ebih0, ebhh0, y0, hs0, 0, TT);

  // encoder layer 1: time-chunked gi GEMM + scan
  const long BSTR = (long)TT * 512;  // per-b element stride in y0
  for (int c = 0; c < TT / CHUNK; ++c) {
    const int t0 = c * CHUNK;
    k_gemm<<<dim3(BB * CHUNK / 64, 12), 256, 0, stream>>>(
        y0 + (size_t)t0 * 512, wih1_16, gi, ebih1,
        512, 6, BSTR, 512, 1536, 0);
    k_gemm<<<dim3(BB * CHUNK / 64, 12), 256, 0, stream>>>(
        y0 + (size_t)(TT - 1 - t0) * 512, wih1_16 + (size_t)768 * 512, gi, ebih1 + 768,
        512, 6, BSTR, -512, 1536, 768);
    k_scan<1><<<256, 512, 0, stream>>>(nullptr, gi, (const uint32_t*)whh1_16,
                                       nullptr, nullptr, ebhh1, y1, hs1, t0, CHUNK);
  }

  // enc = y1 @ e2d^T + b   (writes into y0's region)
  k_gemm<<<dim3(BT / 64, 4), 256, 0, stream>>>(y1, e2d_16, enc, e2db,
                                               512, 30, 0, 512, 256, 0);

  // persistent decoder: one 768-thread WG per batch element, all 63 steps
  k_decoder<<<128, 768, 0, stream>>>(dwhh_16, dwih1_16, dwih0_16, qw_16, outw_16,
                                     enc, dbih, dbhh, qb, outb, emb,
                                     hs0, hs1, tseq, (float*)d_out);
}